// Round 4
// baseline (203.760 us; speedup 1.0000x reference)
//
#include <hip/hip_runtime.h>

// KPConv simple block: grid + wave-autonomous MFMA KPConv + BN + LeakyReLU
// B=8, N=4096 -> M=32768; C_IN=64, C_OUT=128, K=15 kernel pts.
//
// Exact simplification: influence w = max(1 - d/0.04, 0) with ||kp||<=0.042
// => candidates with ||rel|| >= 0.082 contribute 0 to every kernel point;
// the within-0.082 set == reference top-k result.
//
// R16: stage-1 rebuilt wave-autonomous (R12-R15 were barrier-lockstep:
// ~25 barriers/block, 2.8 waves/SIMD avg, 65% no-issue stall; all three
// R15 latency fixes nulled because vmcnt drains at each barrier anyway).
//  - each wave owns 4 consecutive queries: private bbox/search/union
//    (ballot-compacted, register counter, no atomics), private S/FT LDS,
//    private 4x4 MFMA chain. ZERO stage-1 barriers; 2 barriers/block total.
//  - union per 4q ~30 (vs ~70-130 per 16q): ~2.3x fewer pair evals,
//    typically ONE 32-chunk.
//  - S-fill lane=(q,k) evaluates 32 n -> vectorized b128 S writes; kp in
//    per-lane registers.
//  - stage-2 / wf swizzle / Wt k-major / BN partials unchanged (verified).
//  LDS 49.2 KB -> 3 blocks/CU (12 independent waves).

#define NB     8
#define NPTS   4096
#define M_TOT  32768
#define CIN    64
#define COUT   128
#define NKP    15
#define NCELL  1728            // 12^3
#define UCAP4  128             // per-wave union cap (mean ~30)
#define R2EFF  (0.082f * 0.082f)
#define KP_INV 25.0f           // 1 / KP_EXTENT(0.04)
#define NEG_SLOPE 0.2f
#define KCP    960             // kc' = k*64+c, k-major, k=15 dropped
#define WFROW  1920            // wf row stride bytes (960 bf16)
#define SP     40              // S/FT row stride (shorts), 80B
#define WSTRIDE 12288          // per-wave LDS slice bytes

typedef float f32x4_t __attribute__((ext_vector_type(4)));
typedef short bf16x8_t __attribute__((ext_vector_type(8)));

__device__ __forceinline__ unsigned short f2bf(float f) {
  union { float f; unsigned u; } v; v.f = f;
  unsigned r = v.u + 0x7FFF + ((v.u >> 16) & 1);   // RNE
  return (unsigned short)(r >> 16);
}
// half-up rounding: same 0.5 ulp max error as RNE, 2 VALU ops
__device__ __forceinline__ unsigned short f2bf_fast(float f) {
  union { float f; unsigned u; } v; v.f = f;
  return (unsigned short)((v.u + 0x8000u) >> 16);
}
__device__ __forceinline__ int cell_of(float x, float y, float z) {
  int cx = (int)(x * 12.f); cx = cx > 11 ? 11 : cx;
  int cy = (int)(y * 12.f); cy = cy > 11 ? 11 : cy;
  int cz = (int)(z * 12.f); cz = cz > 11 ? 11 : cz;
  return (cz * 12 + cy) * 12 + cx;
}
__device__ __forceinline__ int cix(float v) {
  int c = (int)(v * 12.f); return c > 11 ? 11 : c;
}

// ---------------------------------------------------------------------------
// K0a: per-cell histogram
// ---------------------------------------------------------------------------
__global__ __launch_bounds__(256) void k0a_hist(
    const float* __restrict__ xyz, int* __restrict__ cellcnt)
{
  const int pt = blockIdx.x * 256 + threadIdx.x;
  const float x = xyz[pt * 3], y = xyz[pt * 3 + 1], z = xyz[pt * 3 + 2];
  const int b = pt >> 12;
  atomicAdd(&cellcnt[b * NCELL + cell_of(x, y, z)], 1);
}

// ---------------------------------------------------------------------------
// K0b: blocks 0..7 = per-batch exclusive scan; blocks 8..39 = W -> Wt
// Wt[d][k*64+c] bf16, k-major, k=15 dropped (its S rows are zero anyway).
// ---------------------------------------------------------------------------
__global__ __launch_bounds__(256) void k0b_scan_kW(
    const int* __restrict__ cellcnt, int* __restrict__ cellstart,
    const float* __restrict__ W, unsigned short* __restrict__ Wt)
{
  if (blockIdx.x >= 8) {
    const int idx = (blockIdx.x - 8) * 256 + threadIdx.x;  // 8192
    const int c = idx & 63, d = idx >> 6;                  // d 0..127
    #pragma unroll
    for (int k = 0; k < NKP; k++)
      Wt[(size_t)d * KCP + k * 64 + c] =
          f2bf(W[(size_t)k * (CIN * COUT) + c * COUT + d]);
    return;
  }
  __shared__ int ps[256];
  const int b = blockIdx.x, t = threadIdx.x;
  int local[7], s = 0;
  #pragma unroll
  for (int i = 0; i < 7; i++) {
    const int cid = t * 7 + i;
    const int c = (cid < NCELL) ? cellcnt[b * NCELL + cid] : 0;
    local[i] = c; s += c;
  }
  ps[t] = s; __syncthreads();
  for (int off = 1; off < 256; off <<= 1) {
    int v = (t >= off) ? ps[t - off] : 0;
    __syncthreads();
    ps[t] += v;
    __syncthreads();
  }
  int run = ps[t] - s;
  #pragma unroll
  for (int i = 0; i < 7; i++) {
    const int cid = t * 7 + i;
    if (cid < NCELL) { cellstart[b * 1729 + cid] = run; run += local[i]; }
  }
  if (t == 255) cellstart[b * 1729 + NCELL] = ps[255];
}

// ---------------------------------------------------------------------------
// K0c: counting-sort scatter -> qorder + sorted xyz + sorted bf16 feats
// ---------------------------------------------------------------------------
__global__ __launch_bounds__(256) void k0c_scatter(
    const float* __restrict__ xyz, const float* __restrict__ feats,
    const int* __restrict__ cellstart, int* __restrict__ cellfill,
    int* __restrict__ qorder, float4* __restrict__ xyzs,
    unsigned short* __restrict__ fsorted)
{
  const int pt = blockIdx.x * 256 + threadIdx.x;
  const float x = xyz[pt * 3], y = xyz[pt * 3 + 1], z = xyz[pt * 3 + 2];
  const int b = pt >> 12;
  const int cid = cell_of(x, y, z);
  const int slot = atomicAdd(&cellfill[b * NCELL + cid], 1);
  const int pos = b * NPTS + cellstart[b * 1729 + cid] + slot;
  qorder[pos] = pt;
  xyzs[pos] = make_float4(x, y, z, 0.f);
  const float* src = &feats[(size_t)pt * CIN];
  uint4* dst = (uint4*)&fsorted[(size_t)pos * CIN];
  #pragma unroll
  for (int g = 0; g < 8; g++) {
    float4 a = *(const float4*)(src + g * 8);
    float4 c = *(const float4*)(src + g * 8 + 4);
    union { unsigned short s[8]; uint4 v; } u;
    u.s[0] = f2bf(a.x); u.s[1] = f2bf(a.y); u.s[2] = f2bf(a.z); u.s[3] = f2bf(a.w);
    u.s[4] = f2bf(c.x); u.s[5] = f2bf(c.y); u.s[6] = f2bf(c.z); u.s[7] = f2bf(c.w);
    dst[g] = u.v;
  }
}

// ---------------------------------------------------------------------------
// K2: wave-autonomous MFMA KPConv. 2048 blocks x 256 thr (4 waves); each
// wave owns 4 queries (search + union + stage-1, no barriers). Block-level
// only for wf assembly + stage-2. LDS 49.2 KB -> 3 blocks/CU.
// ---------------------------------------------------------------------------
__global__ __launch_bounds__(256, 3) void k2_conv(
    const float4* __restrict__ xyzs, const unsigned short* __restrict__ fsorted,
    const float* __restrict__ kpts, const int* __restrict__ cellstart,
    const int* __restrict__ qorder, const unsigned short* __restrict__ Wt,
    float* __restrict__ out, float* __restrict__ psum,
    float* __restrict__ psumsq)
{
  // per-wave slice (12288 B): S[64][40]sh @0, FT[64][40]sh @5120,
  // Pu float4[128] @10240.  After stage-1 barrier the whole 49152 B is
  // reused as wf[16] rows x 1920 B (k-major, XOR-swizzled).
  __shared__ char smraw[49152] __attribute__((aligned(16)));
  __shared__ int qm[16];

  const int tid = threadIdx.x;
  const int w   = tid >> 6;
  const int L   = tid & 63;
  const int m0  = blockIdx.x * 16;
  const int b   = m0 >> 12;

  char* wbase = smraw + w * WSTRIDE;
  short (*S)[SP]  = (short(*)[SP])wbase;
  short (*FT)[SP] = (short(*)[SP])(wbase + 5120);
  float4* Pu      = (float4*)(wbase + 10240);

  // per-lane kernel-point constants: lane's k = L&15 (k=15 -> zero row)
  const int kk_ = L & 15;
  float k2x = 0.f, k2y = 0.f, k2z = 0.f, kpc = 0.f;
  if (kk_ < NKP) {
    const float kx = kpts[kk_ * 3], ky = kpts[kk_ * 3 + 1],
                kz = kpts[kk_ * 3 + 2];
    k2x = -2.f * kx; k2y = -2.f * ky; k2z = -2.f * kz;
    kpc = kx * kx + ky * ky + kz * kz;
  }

  // wave's 4 queries
  const int q0g = m0 + w * 4;
  if (L < 4) qm[w * 4 + L] = qorder[q0g + L];
  const float4 Q0 = xyzs[q0g + 0];
  const float4 Q1 = xyzs[q0g + 1];
  const float4 Q2 = xyzs[q0g + 2];
  const float4 Q3 = xyzs[q0g + 3];
  const float4 Qs = xyzs[q0g + (L >> 4)];   // lane's own query (q = L>>4)

  // ---- per-wave bbox (+1 cell) ----
  int cxm = cix(Q0.x), cxM = cxm, cym = cix(Q0.y), cyM = cym,
      czm = cix(Q0.z), czM = czm;
  {
    int v;
    v = cix(Q1.x); cxm = v < cxm ? v : cxm; cxM = v > cxM ? v : cxM;
    v = cix(Q2.x); cxm = v < cxm ? v : cxm; cxM = v > cxM ? v : cxM;
    v = cix(Q3.x); cxm = v < cxm ? v : cxm; cxM = v > cxM ? v : cxM;
    v = cix(Q1.y); cym = v < cym ? v : cym; cyM = v > cyM ? v : cyM;
    v = cix(Q2.y); cym = v < cym ? v : cym; cyM = v > cyM ? v : cyM;
    v = cix(Q3.y); cym = v < cym ? v : cym; cyM = v > cyM ? v : cyM;
    v = cix(Q1.z); czm = v < czm ? v : czm; czM = v > czM ? v : czM;
    v = cix(Q2.z); czm = v < czm ? v : czm; czM = v > czM ? v : czM;
    v = cix(Q3.z); czm = v < czm ? v : czm; czM = v > czM ? v : czM;
  }
  const int x0 = cxm > 0 ? cxm - 1 : 0, x1 = cxM < 11 ? cxM + 1 : 11;
  const int y0 = cym > 0 ? cym - 1 : 0, y1 = cyM < 11 ? cyM + 1 : 11;
  const int z0 = czm > 0 ? czm - 1 : 0, z1 = czM < 11 ? czM + 1 : 11;
  const int yspan = y1 - y0 + 1;
  int nr = yspan * (z1 - z0 + 1);
  nr = nr > 64 ? 64 : nr;

  // row bounds fetched in parallel (lane r holds row r)
  int rs = 0, re = 0;
  if (L < nr) {
    const int zz = z0 + L / yspan, yy = y0 + L % yspan;
    const int base = b * 1729 + (zz * 12 + yy) * 12;
    rs = cellstart[base + x0];
    re = cellstart[base + x1 + 1];
  }

  // ---- per-wave union search: ballot compaction, register counter ----
  int cnt = 0;
  for (int r = 0; r < nr; r++) {
    const int rrs = __shfl(rs, r), rre = __shfl(re, r);
    for (int t0 = rrs; t0 < rre; t0 += 64) {
      const int t = t0 + L;
      bool hit = false;
      float4 P;
      if (t < rre) {
        P = xyzs[b * NPTS + t];
        float dx = P.x - Q0.x, dy = P.y - Q0.y, dz = P.z - Q0.z;
        float best = dx * dx + dy * dy + dz * dz;
        dx = P.x - Q1.x; dy = P.y - Q1.y; dz = P.z - Q1.z;
        float d2 = dx * dx + dy * dy + dz * dz; best = d2 < best ? d2 : best;
        dx = P.x - Q2.x; dy = P.y - Q2.y; dz = P.z - Q2.z;
        d2 = dx * dx + dy * dy + dz * dz; best = d2 < best ? d2 : best;
        dx = P.x - Q3.x; dy = P.y - Q3.y; dz = P.z - Q3.z;
        d2 = dx * dx + dy * dy + dz * dz; best = d2 < best ? d2 : best;
        hit = best <= R2EFF;
      }
      const unsigned long long m = __ballot(hit);
      if (hit) {
        const int slot = cnt + __popcll(m & ((1ull << L) - 1ull));
        if (slot < UCAP4)
          Pu[slot] = make_float4(P.x, P.y, P.z, __int_as_float(t));
      }
      cnt += __popcll(m);
    }
  }
  int U = cnt > UCAP4 ? UCAP4 : cnt;

  // ---- stage-1: per-wave chunked MFMA (no barriers; typ. 1 chunk) ----
  const int ln = L & 15;
  const int kh = L >> 4;

  f32x4_t acc[4][4];
  #pragma unroll
  for (int mt = 0; mt < 4; mt++)
    #pragma unroll
    for (int nt = 0; nt < 4; nt++)
      acc[mt][nt] = (f32x4_t){0.f, 0.f, 0.f, 0.f};

  for (int ub = 0; ub < U; ub += 32) {
    // FT[c][n] fill: lane = channel c = L; coalesced 128B row gathers
    {
      union { unsigned short s[32]; uint4 v[4]; } fu;
      #pragma unroll
      for (int n = 0; n < 32; n++) {
        const int u = ub + n;
        const int uu = u < U ? u : U - 1;
        const int pos = __float_as_int(Pu[uu].w);
        unsigned short v = 0;
        if (u < U) v = fsorted[(size_t)(b * NPTS + pos) * CIN + L];
        fu.s[n] = v;
      }
      uint4* dst = (uint4*)&FT[L][0];
      dst[0] = fu.v[0]; dst[1] = fu.v[1]; dst[2] = fu.v[2]; dst[3] = fu.v[3];
    }
    // S[q*16+k][n] fill: lane = (q = L>>4, k = L&15) -> row L, 32 n serial
    {
      union { unsigned short s[32]; uint4 v[4]; } su;
      #pragma unroll
      for (int n = 0; n < 32; n++) {
        const int u = ub + n;
        const int uu = u < U ? u : U - 1;
        const float4 P = Pu[uu];
        const float rx = P.x - Qs.x, ry = P.y - Qs.y, rz = P.z - Qs.z;
        const float rr = rx * rx + ry * ry + rz * rz;
        float d2 = fmaf(k2x, rx, fmaf(k2y, ry, fmaf(k2z, rz, rr + kpc)));
        d2 = fmaxf(d2, 0.f);
        const float wv =
            fmaxf(fmaf(-KP_INV, __builtin_amdgcn_sqrtf(d2), 1.f), 0.f);
        su.s[n] = (u < U && kk_ < NKP) ? f2bf_fast(wv) : (unsigned short)0;
      }
      uint4* dst = (uint4*)&S[L][0];
      dst[0] = su.v[0]; dst[1] = su.v[1]; dst[2] = su.v[2]; dst[3] = su.v[3];
    }
    // MFMA 4 m-tiles x 4 c-tiles (wave-local LDS; compiler orders lgkmcnt)
    bf16x8_t aa[4], bb[4];
    #pragma unroll
    for (int i = 0; i < 4; i++) {
      aa[i] = *(const bf16x8_t*)&S[i * 16 + ln][kh * 8];
      bb[i] = *(const bf16x8_t*)&FT[i * 16 + ln][kh * 8];
    }
    #pragma unroll
    for (int mt = 0; mt < 4; mt++)
      #pragma unroll
      for (int nt = 0; nt < 4; nt++)
        acc[mt][nt] = __builtin_amdgcn_mfma_f32_16x16x32_bf16(
            aa[mt], bb[nt], acc[mt][nt], 0, 0, 0);
  }

  __syncthreads();   // all waves done with S/FT/Pu; region becomes wf

  // ---- writeback: acc -> wf[q][k*64+c], XOR-swizzled ----
  #pragma unroll
  for (int mt = 0; mt < 4; mt++) {
    const int row = w * 4 + mt;
    const int swz = (row & 7) << 4;
    #pragma unroll
    for (int nt = 0; nt < 4; nt++) {
      const int c = nt * 16 + ln;
      #pragma unroll
      for (int j = 0; j < 4; j++) {
        const int k = kh * 4 + j;
        if (k < 15) {
          const int byteo = (row * WFROW + ((k * 64 + c) << 1)) ^ swz;
          *(unsigned short*)(smraw + byteo) = f2bf_fast(acc[mt][nt][j]);
        }
      }
    }
  }
  __syncthreads();

  // ---- stage-2: out[16][128] = wf[16][960] @ Wt^T ----
  const int colbase = w * 32;

  f32x4_t acc2[2];
  acc2[0] = (f32x4_t){0.f, 0.f, 0.f, 0.f};
  acc2[1] = (f32x4_t){0.f, 0.f, 0.f, 0.f};

  const unsigned short* Bp0 = &Wt[(size_t)(colbase + ln) * KCP + kh * 8];
  const unsigned short* Bp1 = Bp0 + 16 * KCP;
  const char* wfb = (const char*)smraw + ln * WFROW;
  const int   sw  = (ln & 7) << 4;

  #pragma unroll 6
  for (int kk = 0; kk < 30; kk++) {
    const int ko  = kk * 32;
    const int inr = (kh * 16 + kk * 64) ^ sw;
    bf16x8_t b0 = *(const bf16x8_t*)(Bp0 + ko);
    bf16x8_t b1 = *(const bf16x8_t*)(Bp1 + ko);
    bf16x8_t a0 = *(const bf16x8_t*)(wfb + inr);
    acc2[0] = __builtin_amdgcn_mfma_f32_16x16x32_bf16(a0, b0, acc2[0], 0, 0, 0);
    acc2[1] = __builtin_amdgcn_mfma_f32_16x16x32_bf16(a0, b1, acc2[1], 0, 0, 0);
  }

  // BN partials: reduce 16 rows across kh via shfl, atomic into psum[128]
  float s0 = 0.f, q0 = 0.f, s1 = 0.f, q1 = 0.f;
  #pragma unroll
  for (int j = 0; j < 4; j++) {
    s0 += acc2[0][j]; q0 += acc2[0][j] * acc2[0][j];
    s1 += acc2[1][j]; q1 += acc2[1][j] * acc2[1][j];
  }
  s0 += __shfl_xor(s0, 16); s0 += __shfl_xor(s0, 32);
  q0 += __shfl_xor(q0, 16); q0 += __shfl_xor(q0, 32);
  s1 += __shfl_xor(s1, 16); s1 += __shfl_xor(s1, 32);
  q1 += __shfl_xor(q1, 16); q1 += __shfl_xor(q1, 32);
  if (kh == 0) {
    atomicAdd(&psum[colbase + ln], s0);
    atomicAdd(&psumsq[colbase + ln], q0);
    atomicAdd(&psum[colbase + 16 + ln], s1);
    atomicAdd(&psumsq[colbase + 16 + ln], q1);
  }

  // C/D layout: col = lane&15, row = (lane>>4)*4 + reg; scatter via qm[]
  #pragma unroll
  for (int c = 0; c < 2; c++) {
    #pragma unroll
    for (int j = 0; j < 4; j++) {
      const int row = kh * 4 + j;
      out[(size_t)qm[row] * COUT + colbase + c * 16 + ln] = acc2[c][j];
    }
  }
}

// ---------------------------------------------------------------------------
// K4: BN finalize (per-block, from psum) + normalize + LeakyReLU
// ---------------------------------------------------------------------------
__global__ __launch_bounds__(256) void k4_norm(
    float* __restrict__ out, const float* __restrict__ psum,
    const float* __restrict__ psumsq, const float* __restrict__ gamma,
    const float* __restrict__ beta)
{
  __shared__ float a_s[128], b_s[128];
  if (threadIdx.x < 128) {
    const int d = threadIdx.x;
    double mu  = (double)psum[d] / (double)M_TOT;
    double var = (double)psumsq[d] / (double)M_TOT - mu * mu;  // biased
    float rstd = (float)(1.0 / sqrt(var + 1e-5));
    float a = rstd * gamma[d];
    a_s[d] = a;
    b_s[d] = beta[d] - (float)mu * a;
  }
  __syncthreads();
  const int idx = blockIdx.x * 256 + threadIdx.x;   // float4 index
  float4 v = ((const float4*)out)[idx];
  const int d0 = (idx * 4) & 127;
  float y0 = v.x * a_s[d0 + 0] + b_s[d0 + 0];
  float y1 = v.y * a_s[d0 + 1] + b_s[d0 + 1];
  float y2 = v.z * a_s[d0 + 2] + b_s[d0 + 2];
  float y3 = v.w * a_s[d0 + 3] + b_s[d0 + 3];
  v.x = y0 >= 0.f ? y0 : NEG_SLOPE * y0;
  v.y = y1 >= 0.f ? y1 : NEG_SLOPE * y1;
  v.z = y2 >= 0.f ? y2 : NEG_SLOPE * y2;
  v.w = y3 >= 0.f ? y3 : NEG_SLOPE * y3;
  ((float4*)out)[idx] = v;
}

// ---------------------------------------------------------------------------
extern "C" void kernel_launch(void* const* d_in, const int* in_sizes, int n_in,
                              void* d_out, int out_size, void* d_ws,
                              size_t ws_size, hipStream_t stream)
{
  const float* xyz   = (const float*)d_in[0];
  const float* feats = (const float*)d_in[1];
  const float* kpts  = (const float*)d_in[2];
  const float* W     = (const float*)d_in[3];
  const float* gamma = (const float*)d_in[4];
  const float* beta  = (const float*)d_in[5];
  float* out = (float*)d_out;

  char* ws = (char*)d_ws;
  int*            cellcnt   = (int*)(ws + 0);           //  55296 B ─┐
  int*            cellfill  = (int*)(ws + 55296);       //  55296 B  │ zeroed
  float*          psum      = (float*)(ws + 110592);    //    512 B  │
  float*          psumsq    = (float*)(ws + 111104);    //    512 B ─┘
  int*            cellstart = (int*)(ws + 111616);      //  55424 B
  int*            qorder    = (int*)(ws + 167040);      // 131072 B
  float4*         xyzs      = (float4*)(ws + 298112);   // 524288 B
  unsigned short* fsorted   = (unsigned short*)(ws + 822400);   // 4194304 B
  unsigned short* Wt        = (unsigned short*)(ws + 5016704);  // 245760 B

  hipMemsetAsync(ws, 0, 111616, stream);

  k0a_hist   <<< 128, 256, 0, stream>>>(xyz, cellcnt);
  k0b_scan_kW<<<  40, 256, 0, stream>>>(cellcnt, cellstart, W, Wt);
  k0c_scatter<<< 128, 256, 0, stream>>>(xyz, feats, cellstart, cellfill,
                                        qorder, xyzs, fsorted);
  k2_conv    <<<2048, 256, 0, stream>>>(xyzs, fsorted, kpts, cellstart,
                                        qorder, Wt, out, psum, psumsq);
  k4_norm    <<<(out_size / 4) / 256, 256, 0, stream>>>(out, psum, psumsq,
                                                        gamma, beta);
}